// Round 14
// baseline (105.689 us; speedup 1.0000x reference)
//
#include <hip/hip_runtime.h>
#include <stdint.h>

// MeshPoolFace: batched segment-mean pooling.
// fe: [B=16, C=256, F=16000] f32, gid: [B, F] int32 in [0, T=8000)
// out[b][c][t] = mean over {f : gid[b][f]==t} of fe[b][c][f]
//
// Round-21: 2 dispatches. The 512KB memset existed only because hist's
// atomics are cross-block; partitioning by batch removes the hazard:
// zhist = one block per batch (grid=16, 1024thr) zeros its OWN cnt slice,
// __syncthreads (stores drained to the XCD-local L2 that serves the
// atomics), then histograms its 16000 faces + writes occ (u16x4 coalesced).
// All cnt[b] atomic traffic stays in one XCD's L2 — no device-scope sync
// (r18/r11 trap structurally avoided). Pool = r20 (in-kernel scan prologue
// + r16 window loop), with pair-0 fe loads hoisted before prologue B and
// the last prologue barrier as LGKM_BAR (no vmcnt drain).
// Chain: zhist -> pool.

#define NB 16
#define NC 256
#define NF 16000
#define NT 8000
#define CPB 16  // channels per pool block (8 pair-windows); grid = 256

typedef unsigned int uint;
typedef unsigned short ushort;
typedef float f32x4 __attribute__((ext_vector_type(4)));

__device__ __forceinline__ float bf2f(uint h) { return __uint_as_float(h << 16); }
__device__ __forceinline__ uint cvtpk(float lo, float hi) {
    uint r;
    asm("v_cvt_pk_bf16_f32 %0, %1, %2" : "=v"(r) : "v"(lo), "v"(hi));
    return r;
}

// K1: fused zero + histogram + occurrence. grid = NB = 16, 1024 thr.
// Block b owns cnt[b] exclusively -> zero-then-atomic needs only the
// block-local barrier. occ[f] = atomic's old value = occurrence index.
__global__ __launch_bounds__(1024) void zhist_kernel(const int* __restrict__ gid,
                                                     int* __restrict__ cnt,
                                                     ushort* __restrict__ occ) {
    const int b = blockIdx.x, tid = threadIdx.x;
    int* cb = cnt + (size_t)b * NT;

    // zero own slice: 2000 int4
    {
        int4* c4 = (int4*)cb;
        int4 z = make_int4(0, 0, 0, 0);
        c4[tid] = z;
        if (tid < 976) c4[1024 + tid] = z;
    }
    __syncthreads();   // stores drained (vmcnt 0) before any atomic below

    // histogram + occ: 4000 int4 of gid; 4 iters/thread
    const int4* g4 = (const int4*)(gid + (size_t)b * NF);
    ushort4* o4 = (ushort4*)(occ + (size_t)b * NF);
#pragma unroll
    for (int it = 0; it < 4; ++it) {
        int i = tid + it * 1024;
        if (i < 4000) {
            int4 g = g4[i];
            uint a0 = (uint)atomicAdd(&cb[g.x], 1);
            uint a1 = (uint)atomicAdd(&cb[g.y], 1);
            uint a2 = (uint)atomicAdd(&cb[g.z], 1);
            uint a3 = (uint)atomicAdd(&cb[g.w], 1);
            o4[i] = make_ushort4((ushort)a0, (ushort)a1,
                                 (ushort)a2, (ushort)a3);
        }
    }
}

// Raw barrier: drain own LDS ops, workgroup barrier. Never drains vmcnt,
// so global prefetch loads / NT stores stay in flight across it.
#define LGKM_BAR() do {                                          \
        asm volatile("s_waitcnt lgkmcnt(0)" ::: "memory");       \
        __builtin_amdgcn_s_barrier();                            \
        __builtin_amdgcn_sched_barrier(0);                       \
    } while (0)

// K4: pool with in-kernel scan prologue. grid = 256, 1024 thr, 128000 B
// dynamic LDS. Prologue: private scan of cnt[b] -> pkl LDS overlay (buf0's
// first 32KB) -> [issue pair-0 fe loads] -> pv + slot packs in regs ->
// LGKM_BAR -> r16 window loop (buf0 fully overwritten by window-0 scatter).
__global__ __launch_bounds__(1024) void pool_kernel(const float* __restrict__ fe,
                                                    const int* __restrict__ gid,
                                                    const ushort* __restrict__ occ,
                                                    const int* __restrict__ cnt,
                                                    float* __restrict__ out) {
    extern __shared__ char smem[];
    uint* fes32 = (uint*)smem;          // 2 x 16000 u32 window buffers
    uint* pkl = (uint*)smem;            // prologue overlay: pkl[8000] (32KB)
    int* wpart = (int*)(smem + 64000);  // 16 wave partials (buf1 region)
    const int bid = blockIdx.x;
    const int b = bid >> 4, cg = bid & 15;
    const int tid = threadIdx.x;
    const int lane = tid & 63, wid = tid >> 6;
    const size_t bc0 = (size_t)(b * NC + cg * CPB);
    const bool t3 = (tid < 928);     // face tail: 4000 f32x4 per channel
    const bool t8 = (tid < 832);     // group tail: 8000 groups
    const int tl = t3 ? tid + 3072 : tid;   // uniform-load index (dummy=tid)

    // ---- prologue A: block-private exclusive scan of cnt[b] -> pkl ----
    // 1000 active threads x 8 counts; two-level scan (wave shfl + partials).
    int loc[8], nv[8];
    int ts = 0;
    if (tid < 1000) {
        const int4* c4 = (const int4*)(cnt + (size_t)b * NT + 8 * tid);
        int4 v0 = c4[0], v1 = c4[1];
        loc[0] = ts; nv[0] = v0.x; ts += v0.x;
        loc[1] = ts; nv[1] = v0.y; ts += v0.y;
        loc[2] = ts; nv[2] = v0.z; ts += v0.z;
        loc[3] = ts; nv[3] = v0.w; ts += v0.w;
        loc[4] = ts; nv[4] = v1.x; ts += v1.x;
        loc[5] = ts; nv[5] = v1.y; ts += v1.y;
        loc[6] = ts; nv[6] = v1.z; ts += v1.z;
        loc[7] = ts; nv[7] = v1.w; ts += v1.w;
    }
    int inc = ts;
    for (int d = 1; d < 64; d <<= 1) {
        int u = __shfl_up(inc, d);
        if (lane >= d) inc += u;
    }
    if (lane == 63) wpart[wid] = inc;
    __syncthreads();
    {
        int wbase = 0;
        for (int wv = 0; wv < wid; ++wv) wbase += wpart[wv];  // broadcast reads
        int base = wbase + inc - ts;   // exclusive prefix for this thread
        if (tid < 1000) {
#pragma unroll
            for (int j = 0; j < 8; ++j)
                pkl[8 * tid + j] = (uint)(base + loc[j]) | ((uint)nv[j] << 14);
        }
    }
    __syncthreads();   // pkl complete

    // ---- issue pair-0 fe loads: latency hides under prologue B ----
    const f32x4* fe4base = (const f32x4*)(fe + bc0 * NF);
    f32x4 a0, a1, a2, a3, b0, b1, b2, b3;
    {
        const f32x4* fA = fe4base;
        const f32x4* fB = fe4base + (NF / 4);
        a0 = fA[tid]; a1 = fA[tid + 1024]; a2 = fA[tid + 2048]; a3 = fA[tl];
        b0 = fB[tid]; b1 = fB[tid + 1024]; b2 = fB[tid + 2048]; b3 = fB[tl];
    }

    // ---- prologue B: pv + slot packs from pkl/gid/occ ----
    uint pv[8];
#pragma unroll
    for (int it = 0; it < 7; ++it) pv[it] = pkl[tid + it * 1024];
    pv[7] = 0;
    if (t8) pv[7] = pkl[7168 + tid];

    uint2 s0, s1, s2, s3;
    {
        const int4* g4 = (const int4*)(gid + (size_t)b * NF);
        const ushort4* o4 = (const ushort4*)(occ + (size_t)b * NF);
        int4 ga = g4[tid], gb4 = g4[tid + 1024];
        int4 gc = g4[tid + 2048], gd = g4[tl];
        ushort4 oa = o4[tid], ob = o4[tid + 1024];
        ushort4 oc = o4[tid + 2048], od = o4[tl];
#define SLOT(G, O) ((pkl[(uint)(G)] & 0x3FFFu) + (uint)(O))
        s0 = make_uint2(SLOT(ga.x, oa.x) | (SLOT(ga.y, oa.y) << 16),
                        SLOT(ga.z, oa.z) | (SLOT(ga.w, oa.w) << 16));
        s1 = make_uint2(SLOT(gb4.x, ob.x) | (SLOT(gb4.y, ob.y) << 16),
                        SLOT(gb4.z, ob.z) | (SLOT(gb4.w, ob.w) << 16));
        s2 = make_uint2(SLOT(gc.x, oc.x) | (SLOT(gc.y, oc.y) << 16),
                        SLOT(gc.z, oc.z) | (SLOT(gc.w, oc.w) << 16));
        s3 = make_uint2(SLOT(gd.x, od.x) | (SLOT(gd.y, od.y) << 16),
                        SLOT(gd.z, od.z) | (SLOT(gd.w, od.w) << 16));
#undef SLOT
    }
    LGKM_BAR();   // pkl reads done; buf0 free; fe loads stay in flight

    // ---- r16 window loop (byte-identical) ----
#define PAIR_WRITE(F, S, VA, VB) do {                                    \
        (F)[(S).x & 0xFFFFu] = cvtpk((VA)[0], (VB)[0]);                  \
        (F)[(S).x >> 16]     = cvtpk((VA)[1], (VB)[1]);                  \
        (F)[(S).y & 0xFFFFu] = cvtpk((VA)[2], (VB)[2]);                  \
        (F)[(S).y >> 16]     = cvtpk((VA)[3], (VB)[3]);                  \
    } while (0)

// Paired gather + direct coalesced NT dword stores (consecutive t across
// consecutive threads -> wave stores 256B contiguous, full lines).
#define GATHER_ST(F, P, T) do {                                          \
        uint p_ = (P);                                                   \
        uint off_ = p_ & 0x3FFFu, n_ = p_ >> 14;                         \
        float sa_ = 0.f, sb_ = 0.f;                                      \
        uint r_ = 0;                                                     \
        for (; r_ + 2 <= n_; r_ += 2) {                                  \
            uint2 w_;                                                    \
            __builtin_memcpy(&w_, &(F)[off_ + r_], 8);                   \
            sa_ += bf2f(w_.x & 0xFFFFu) + bf2f(w_.y & 0xFFFFu);          \
            sb_ += bf2f(w_.x >> 16) + bf2f(w_.y >> 16);                  \
        }                                                                \
        if (r_ < n_) {                                                   \
            uint w_ = (F)[off_ + r_];                                    \
            sa_ += bf2f(w_ & 0xFFFFu);                                   \
            sb_ += bf2f(w_ >> 16);                                       \
        }                                                                \
        float rn_ = n_ ? __builtin_amdgcn_rcpf((float)n_) : 0.f;         \
        __builtin_nontemporal_store(sa_ * rn_, &oA[T]);                  \
        __builtin_nontemporal_store(sb_ * rn_, &oB[T]);                  \
    } while (0)

#pragma unroll
    for (int k = 0; k < CPB / 2; ++k) {
        uint* F = fes32 + (k & 1) * 16000;

        // scatter pair k into buf(k&1); gather(k-1) read buf((k-1)&1) — no
        // conflict; barrier at window k-1 ordered gather(k-2) before this.
        PAIR_WRITE(F, s0, a0, b0);
        PAIR_WRITE(F, s1, a1, b1);
        PAIR_WRITE(F, s2, a2, b2);
        if (t3) PAIR_WRITE(F, s3, a3, b3);

        // prefetch next pair: uniform 8 loads, in flight across the window
        if (k + 1 < CPB / 2) {
            const f32x4* fA = fe4base + (size_t)(2 * k + 2) * (NF / 4);
            const f32x4* fB = fA + (NF / 4);
            a0 = fA[tid]; a1 = fA[tid + 1024]; a2 = fA[tid + 2048]; a3 = fA[tl];
            b0 = fB[tid]; b1 = fB[tid + 1024]; b2 = fB[tid + 2048]; b3 = fB[tl];
        }

        LGKM_BAR();   // scatter(k) visible to all; gather(k-1) complete too

        // gather + store means for both channels of pair k
        float* oA = out + (bc0 + (size_t)(2 * k)) * NT;
        float* oB = out + (bc0 + (size_t)(2 * k + 1)) * NT;
#pragma unroll
        for (int it = 0; it < 7; ++it) GATHER_ST(F, pv[it], tid + it * 1024);
        if (t8) GATHER_ST(F, pv[7], 7168 + tid);
    }
#undef GATHER_ST
#undef PAIR_WRITE
}

// Fallback (round-2 path) if workspace is too small.
__device__ __forceinline__ void lds_fadd(unsigned addr, float v) {
    asm volatile("ds_add_f32 %0, %1" :: "v"(addr), "v"(v));
}
__global__ __launch_bounds__(256) void pool_fused_kernel(const float* __restrict__ fe,
                                                         const int* __restrict__ gid,
                                                         float* __restrict__ out) {
    __shared__ float acc[NT];
    __shared__ int cnt[NT];
    const int bc = blockIdx.x, b = bc >> 8, tid = threadIdx.x;
    for (int t = tid; t < NT; t += 256) { acc[t] = 0.0f; cnt[t] = 0; }
    __syncthreads();
    const unsigned accb = (unsigned)(uintptr_t)acc;
    const float4* fe4 = (const float4*)(fe + (size_t)bc * NF);
    const int4* gid4 = (const int4*)(gid + (size_t)b * NF);
    for (int i = tid; i < NF / 4; i += 256) {
        float4 v = fe4[i];
        int4 g = gid4[i];
        lds_fadd(accb + 4u * (unsigned)g.x, v.x); atomicAdd(&cnt[g.x], 1);
        lds_fadd(accb + 4u * (unsigned)g.y, v.y); atomicAdd(&cnt[g.y], 1);
        lds_fadd(accb + 4u * (unsigned)g.z, v.z); atomicAdd(&cnt[g.z], 1);
        lds_fadd(accb + 4u * (unsigned)g.w, v.w); atomicAdd(&cnt[g.w], 1);
    }
    asm volatile("s_waitcnt lgkmcnt(0)" ::: "memory");
    __syncthreads();
    float* orow = out + (size_t)bc * NT;
    for (int t = tid; t < NT; t += 256) {
        int n = cnt[t];
        orow[t] = acc[t] / (float)(n > 0 ? n : 1);
    }
}

extern "C" void kernel_launch(void* const* d_in, const int* in_sizes, int n_in,
                              void* d_out, int out_size, void* d_ws, size_t ws_size,
                              hipStream_t stream) {
    const float* fe = (const float*)d_in[0];
    const int* gid = (const int*)d_in[1];
    float* out = (float*)d_out;

    // workspace layout (bytes)
    const size_t O_CNT = 0;          // int [NB*NT]   512000
    const size_t O_OCC = 512000;     // u16 [NB*NF]   512000
    const size_t TOTAL = 1024000;

    if (ws_size >= TOTAL) {
        char* w = (char*)d_ws;
        int* cnt = (int*)(w + O_CNT);
        ushort* occ = (ushort*)(w + O_OCC);

        static bool lds_opted = false;
        if (!lds_opted) {
            (void)hipFuncSetAttribute((const void*)pool_kernel,
                                      hipFuncAttributeMaxDynamicSharedMemorySize,
                                      128000);
            lds_opted = true;
        }

        zhist_kernel<<<NB, 1024, 0, stream>>>(gid, cnt, occ);
        pool_kernel<<<NB * (NC / CPB), 1024, 128000, stream>>>(fe, gid, occ, cnt, out);
    } else {
        pool_fused_kernel<<<NB * NC, 256, 0, stream>>>(fe, gid, out);
    }
}

// Round 15
// 95.527 us; speedup vs baseline: 1.1064x; 1.1064x over previous
//
#include <hip/hip_runtime.h>
#include <stdint.h>

// MeshPoolFace: batched segment-mean pooling.
// fe: [B=16, C=256, F=16000] f32, gid: [B, F] int32 in [0, T=8000)
// out[b][c][t] = mean over {f : gid[b][f]==t} of fe[b][c][f]
//
// Round-22: r21's zhist (grid=16) REGRESSED 93.6->105.7: concentrating a
// batch's 16000 atomics+occ stores on ONE CU serializes at the L2 atomic
// issue path; r20's 250-block hist spreads them over 250 CUs. (Session
// lesson, 3rd confirmation: spread atomics win, concentrated atomics lose.)
// Chain reverted to r20: memset(512K) -> hist(250 blk, +occ) -> pool.
// This round isolates the r21 pool micro-fix (never measured alone):
//   - pair-0 fe loads issued BEFORE prologue B (latency hides under
//     slot-pack ALU)
//   - final prologue barrier = LGKM_BAR (no vmcnt drain of those loads)
// Window loop = r16 champion, byte-identical.

#define NB 16
#define NC 256
#define NF 16000
#define NT 8000
#define CPB 16  // channels per pool block (8 pair-windows); grid = 256

typedef unsigned int uint;
typedef unsigned short ushort;
typedef float f32x4 __attribute__((ext_vector_type(4)));

__device__ __forceinline__ float bf2f(uint h) { return __uint_as_float(h << 16); }
__device__ __forceinline__ uint cvtpk(float lo, float hi) {
    uint r;
    asm("v_cvt_pk_bf16_f32 %0, %1, %2" : "=v"(r) : "v"(lo), "v"(hi));
    return r;
}

// K1: histogram + occurrence index. grid = 250 (spread atomics over CUs).
// occ[f] = old count from the atomic = unique index in [0, n(g)) per face.
__global__ __launch_bounds__(256) void hist_kernel(const int* __restrict__ gid,
                                                   int* __restrict__ cnt,
                                                   ushort* __restrict__ occ) {
    int i = blockIdx.x * 256 + threadIdx.x;
    if (i >= NB * NF / 4) return;
    int4 g = ((const int4*)gid)[i];
    int* c = cnt + (i / (NF / 4)) * NT;
    uint o0 = (uint)atomicAdd(&c[g.x], 1);
    uint o1 = (uint)atomicAdd(&c[g.y], 1);
    uint o2 = (uint)atomicAdd(&c[g.z], 1);
    uint o3 = (uint)atomicAdd(&c[g.w], 1);
    ((ushort4*)occ)[i] = make_ushort4((ushort)o0, (ushort)o1,
                                      (ushort)o2, (ushort)o3);
}

// Raw barrier: drain own LDS ops, workgroup barrier. Never drains vmcnt,
// so global prefetch loads / NT stores stay in flight across it.
#define LGKM_BAR() do {                                          \
        asm volatile("s_waitcnt lgkmcnt(0)" ::: "memory");       \
        __builtin_amdgcn_s_barrier();                            \
        __builtin_amdgcn_sched_barrier(0);                       \
    } while (0)

// K4: pool with in-kernel scan prologue. grid = 256, 1024 thr, 128000 B
// dynamic LDS. Prologue: private scan of cnt[b] -> pkl LDS overlay (buf0's
// first 32KB) -> [issue pair-0 fe loads] -> pv + slot packs in regs ->
// LGKM_BAR -> r16 window loop (buf0 fully overwritten by window-0 scatter).
__global__ __launch_bounds__(1024) void pool_kernel(const float* __restrict__ fe,
                                                    const int* __restrict__ gid,
                                                    const ushort* __restrict__ occ,
                                                    const int* __restrict__ cnt,
                                                    float* __restrict__ out) {
    extern __shared__ char smem[];
    uint* fes32 = (uint*)smem;          // 2 x 16000 u32 window buffers
    uint* pkl = (uint*)smem;            // prologue overlay: pkl[8000] (32KB)
    int* wpart = (int*)(smem + 64000);  // 16 wave partials (buf1 region)
    const int bid = blockIdx.x;
    const int b = bid >> 4, cg = bid & 15;
    const int tid = threadIdx.x;
    const int lane = tid & 63, wid = tid >> 6;
    const size_t bc0 = (size_t)(b * NC + cg * CPB);
    const bool t3 = (tid < 928);     // face tail: 4000 f32x4 per channel
    const bool t8 = (tid < 832);     // group tail: 8000 groups
    const int tl = t3 ? tid + 3072 : tid;   // uniform-load index (dummy=tid)

    // ---- prologue A: block-private exclusive scan of cnt[b] -> pkl ----
    // 1000 active threads x 8 counts; two-level scan (wave shfl + partials).
    int loc[8], nv[8];
    int ts = 0;
    if (tid < 1000) {
        const int4* c4 = (const int4*)(cnt + (size_t)b * NT + 8 * tid);
        int4 v0 = c4[0], v1 = c4[1];
        loc[0] = ts; nv[0] = v0.x; ts += v0.x;
        loc[1] = ts; nv[1] = v0.y; ts += v0.y;
        loc[2] = ts; nv[2] = v0.z; ts += v0.z;
        loc[3] = ts; nv[3] = v0.w; ts += v0.w;
        loc[4] = ts; nv[4] = v1.x; ts += v1.x;
        loc[5] = ts; nv[5] = v1.y; ts += v1.y;
        loc[6] = ts; nv[6] = v1.z; ts += v1.z;
        loc[7] = ts; nv[7] = v1.w; ts += v1.w;
    }
    int inc = ts;
    for (int d = 1; d < 64; d <<= 1) {
        int u = __shfl_up(inc, d);
        if (lane >= d) inc += u;
    }
    if (lane == 63) wpart[wid] = inc;
    __syncthreads();
    {
        int wbase = 0;
        for (int wv = 0; wv < wid; ++wv) wbase += wpart[wv];  // broadcast reads
        int base = wbase + inc - ts;   // exclusive prefix for this thread
        if (tid < 1000) {
#pragma unroll
            for (int j = 0; j < 8; ++j)
                pkl[8 * tid + j] = (uint)(base + loc[j]) | ((uint)nv[j] << 14);
        }
    }
    __syncthreads();   // pkl complete

    // ---- issue pair-0 fe loads: latency hides under prologue B ----
    const f32x4* fe4base = (const f32x4*)(fe + bc0 * NF);
    f32x4 a0, a1, a2, a3, b0, b1, b2, b3;
    {
        const f32x4* fA = fe4base;
        const f32x4* fB = fe4base + (NF / 4);
        a0 = fA[tid]; a1 = fA[tid + 1024]; a2 = fA[tid + 2048]; a3 = fA[tl];
        b0 = fB[tid]; b1 = fB[tid + 1024]; b2 = fB[tid + 2048]; b3 = fB[tl];
    }

    // ---- prologue B: pv + slot packs from pkl/gid/occ ----
    uint pv[8];
#pragma unroll
    for (int it = 0; it < 7; ++it) pv[it] = pkl[tid + it * 1024];
    pv[7] = 0;
    if (t8) pv[7] = pkl[7168 + tid];

    uint2 s0, s1, s2, s3;
    {
        const int4* g4 = (const int4*)(gid + (size_t)b * NF);
        const ushort4* o4 = (const ushort4*)(occ + (size_t)b * NF);
        int4 ga = g4[tid], gb4 = g4[tid + 1024];
        int4 gc = g4[tid + 2048], gd = g4[tl];
        ushort4 oa = o4[tid], ob = o4[tid + 1024];
        ushort4 oc = o4[tid + 2048], od = o4[tl];
#define SLOT(G, O) ((pkl[(uint)(G)] & 0x3FFFu) + (uint)(O))
        s0 = make_uint2(SLOT(ga.x, oa.x) | (SLOT(ga.y, oa.y) << 16),
                        SLOT(ga.z, oa.z) | (SLOT(ga.w, oa.w) << 16));
        s1 = make_uint2(SLOT(gb4.x, ob.x) | (SLOT(gb4.y, ob.y) << 16),
                        SLOT(gb4.z, ob.z) | (SLOT(gb4.w, ob.w) << 16));
        s2 = make_uint2(SLOT(gc.x, oc.x) | (SLOT(gc.y, oc.y) << 16),
                        SLOT(gc.z, oc.z) | (SLOT(gc.w, oc.w) << 16));
        s3 = make_uint2(SLOT(gd.x, od.x) | (SLOT(gd.y, od.y) << 16),
                        SLOT(gd.z, od.z) | (SLOT(gd.w, od.w) << 16));
#undef SLOT
    }
    LGKM_BAR();   // pkl reads done; buf0 free; fe loads stay in flight

    // ---- r16 window loop (byte-identical) ----
#define PAIR_WRITE(F, S, VA, VB) do {                                    \
        (F)[(S).x & 0xFFFFu] = cvtpk((VA)[0], (VB)[0]);                  \
        (F)[(S).x >> 16]     = cvtpk((VA)[1], (VB)[1]);                  \
        (F)[(S).y & 0xFFFFu] = cvtpk((VA)[2], (VB)[2]);                  \
        (F)[(S).y >> 16]     = cvtpk((VA)[3], (VB)[3]);                  \
    } while (0)

// Paired gather + direct coalesced NT dword stores (consecutive t across
// consecutive threads -> wave stores 256B contiguous, full lines).
#define GATHER_ST(F, P, T) do {                                          \
        uint p_ = (P);                                                   \
        uint off_ = p_ & 0x3FFFu, n_ = p_ >> 14;                         \
        float sa_ = 0.f, sb_ = 0.f;                                      \
        uint r_ = 0;                                                     \
        for (; r_ + 2 <= n_; r_ += 2) {                                  \
            uint2 w_;                                                    \
            __builtin_memcpy(&w_, &(F)[off_ + r_], 8);                   \
            sa_ += bf2f(w_.x & 0xFFFFu) + bf2f(w_.y & 0xFFFFu);          \
            sb_ += bf2f(w_.x >> 16) + bf2f(w_.y >> 16);                  \
        }                                                                \
        if (r_ < n_) {                                                   \
            uint w_ = (F)[off_ + r_];                                    \
            sa_ += bf2f(w_ & 0xFFFFu);                                   \
            sb_ += bf2f(w_ >> 16);                                       \
        }                                                                \
        float rn_ = n_ ? __builtin_amdgcn_rcpf((float)n_) : 0.f;         \
        __builtin_nontemporal_store(sa_ * rn_, &oA[T]);                  \
        __builtin_nontemporal_store(sb_ * rn_, &oB[T]);                  \
    } while (0)

#pragma unroll
    for (int k = 0; k < CPB / 2; ++k) {
        uint* F = fes32 + (k & 1) * 16000;

        // scatter pair k into buf(k&1); gather(k-1) read buf((k-1)&1) — no
        // conflict; barrier at window k-1 ordered gather(k-2) before this.
        PAIR_WRITE(F, s0, a0, b0);
        PAIR_WRITE(F, s1, a1, b1);
        PAIR_WRITE(F, s2, a2, b2);
        if (t3) PAIR_WRITE(F, s3, a3, b3);

        // prefetch next pair: uniform 8 loads, in flight across the window
        if (k + 1 < CPB / 2) {
            const f32x4* fA = fe4base + (size_t)(2 * k + 2) * (NF / 4);
            const f32x4* fB = fA + (NF / 4);
            a0 = fA[tid]; a1 = fA[tid + 1024]; a2 = fA[tid + 2048]; a3 = fA[tl];
            b0 = fB[tid]; b1 = fB[tid + 1024]; b2 = fB[tid + 2048]; b3 = fB[tl];
        }

        LGKM_BAR();   // scatter(k) visible to all; gather(k-1) complete too

        // gather + store means for both channels of pair k
        float* oA = out + (bc0 + (size_t)(2 * k)) * NT;
        float* oB = out + (bc0 + (size_t)(2 * k + 1)) * NT;
#pragma unroll
        for (int it = 0; it < 7; ++it) GATHER_ST(F, pv[it], tid + it * 1024);
        if (t8) GATHER_ST(F, pv[7], 7168 + tid);
    }
#undef GATHER_ST
#undef PAIR_WRITE
}

// Fallback (round-2 path) if workspace is too small.
__device__ __forceinline__ void lds_fadd(unsigned addr, float v) {
    asm volatile("ds_add_f32 %0, %1" :: "v"(addr), "v"(v));
}
__global__ __launch_bounds__(256) void pool_fused_kernel(const float* __restrict__ fe,
                                                         const int* __restrict__ gid,
                                                         float* __restrict__ out) {
    __shared__ float acc[NT];
    __shared__ int cnt[NT];
    const int bc = blockIdx.x, b = bc >> 8, tid = threadIdx.x;
    for (int t = tid; t < NT; t += 256) { acc[t] = 0.0f; cnt[t] = 0; }
    __syncthreads();
    const unsigned accb = (unsigned)(uintptr_t)acc;
    const float4* fe4 = (const float4*)(fe + (size_t)bc * NF);
    const int4* gid4 = (const int4*)(gid + (size_t)b * NF);
    for (int i = tid; i < NF / 4; i += 256) {
        float4 v = fe4[i];
        int4 g = gid4[i];
        lds_fadd(accb + 4u * (unsigned)g.x, v.x); atomicAdd(&cnt[g.x], 1);
        lds_fadd(accb + 4u * (unsigned)g.y, v.y); atomicAdd(&cnt[g.y], 1);
        lds_fadd(accb + 4u * (unsigned)g.z, v.z); atomicAdd(&cnt[g.z], 1);
        lds_fadd(accb + 4u * (unsigned)g.w, v.w); atomicAdd(&cnt[g.w], 1);
    }
    asm volatile("s_waitcnt lgkmcnt(0)" ::: "memory");
    __syncthreads();
    float* orow = out + (size_t)bc * NT;
    for (int t = tid; t < NT; t += 256) {
        int n = cnt[t];
        orow[t] = acc[t] / (float)(n > 0 ? n : 1);
    }
}

extern "C" void kernel_launch(void* const* d_in, const int* in_sizes, int n_in,
                              void* d_out, int out_size, void* d_ws, size_t ws_size,
                              hipStream_t stream) {
    const float* fe = (const float*)d_in[0];
    const int* gid = (const int*)d_in[1];
    float* out = (float*)d_out;

    // workspace layout (bytes)
    const size_t O_CNT = 0;          // int [NB*NT]   512000  (zeroed)
    const size_t O_OCC = 512000;     // u16 [NB*NF]   512000
    const size_t TOTAL = 1024000;

    if (ws_size >= TOTAL) {
        char* w = (char*)d_ws;
        int* cnt = (int*)(w + O_CNT);
        ushort* occ = (ushort*)(w + O_OCC);

        static bool lds_opted = false;
        if (!lds_opted) {
            (void)hipFuncSetAttribute((const void*)pool_kernel,
                                      hipFuncAttributeMaxDynamicSharedMemorySize,
                                      128000);
            lds_opted = true;
        }

        (void)hipMemsetAsync(cnt, 0, 512000, stream);
        hist_kernel<<<(NB * NF / 4 + 255) / 256, 256, 0, stream>>>(gid, cnt, occ);
        pool_kernel<<<NB * (NC / CPB), 1024, 128000, stream>>>(fe, gid, occ, cnt, out);
    } else {
        pool_fused_kernel<<<NB * NC, 256, 0, stream>>>(fe, gid, out);
    }
}

// Round 16
// 95.306 us; speedup vs baseline: 1.1089x; 1.0023x over previous
//
#include <hip/hip_runtime.h>
#include <stdint.h>

// MeshPoolFace: batched segment-mean pooling.
// fe: [B=16, C=256, F=16000] f32, gid: [B, F] int32 in [0, T=8000)
// out[b][c][t] = mean over {f : gid[b][f]==t} of fe[b][c][f]
//
// Round-23: FULL REVERT to the round-20 champion (93.6us) after r22's
// isolated pool micro-fix measured negative (95.5us): hoisting pair-0
// loads before prologue B extended live ranges across the slot-pack ALU
// and cost more than the (off-critical-path) vmcnt drain it avoided.
//
// Champion structure (127.7 -> 93.6us over the session):
//   memset(512K cnt) -> hist(250 blk: atomicAdd returns occ, packed u16x4)
//   -> pool(grid 256, 1024thr, 128KB LDS):
//      prologue A: block-private two-level shfl scan of cnt[b] -> pkl
//                  (LDS overlay of window buf0)
//      prologue B: pv + slot packs in registers from pkl/gid/occ
//      window loop (r16): 8 pair-windows, double-buffered fes32,
//        scatter(cvtpk bf16x2) / prefetch / LGKM_BAR / paired ds_read2
//        gather / direct coalesced NT dword stores. One barrier/window.
// Falsified alternatives: LDS scatter-add (r11, 3cyc/lane), ballot rank
// (r14), quad-pack single-buffer (r17), device-scope grid barriers (r18),
// concentrated zhist (r21), load-hoist micro-fix (r22).

#define NB 16
#define NC 256
#define NF 16000
#define NT 8000
#define CPB 16  // channels per pool block (8 pair-windows); grid = 256

typedef unsigned int uint;
typedef unsigned short ushort;
typedef float f32x4 __attribute__((ext_vector_type(4)));

__device__ __forceinline__ float bf2f(uint h) { return __uint_as_float(h << 16); }
__device__ __forceinline__ uint cvtpk(float lo, float hi) {
    uint r;
    asm("v_cvt_pk_bf16_f32 %0, %1, %2" : "=v"(r) : "v"(lo), "v"(hi));
    return r;
}

// K1: histogram + occurrence index. grid = 250 (spread atomics over CUs).
// occ[f] = old count from the atomic = unique index in [0, n(g)) per face.
__global__ __launch_bounds__(256) void hist_kernel(const int* __restrict__ gid,
                                                   int* __restrict__ cnt,
                                                   ushort* __restrict__ occ) {
    int i = blockIdx.x * 256 + threadIdx.x;
    if (i >= NB * NF / 4) return;
    int4 g = ((const int4*)gid)[i];
    int* c = cnt + (i / (NF / 4)) * NT;
    uint o0 = (uint)atomicAdd(&c[g.x], 1);
    uint o1 = (uint)atomicAdd(&c[g.y], 1);
    uint o2 = (uint)atomicAdd(&c[g.z], 1);
    uint o3 = (uint)atomicAdd(&c[g.w], 1);
    ((ushort4*)occ)[i] = make_ushort4((ushort)o0, (ushort)o1,
                                      (ushort)o2, (ushort)o3);
}

// Raw barrier: drain own LDS ops, workgroup barrier. Never drains vmcnt,
// so global prefetch loads / NT stores stay in flight across it.
#define LGKM_BAR() do {                                          \
        asm volatile("s_waitcnt lgkmcnt(0)" ::: "memory");       \
        __builtin_amdgcn_s_barrier();                            \
        __builtin_amdgcn_sched_barrier(0);                       \
    } while (0)

// K4: pool with in-kernel scan prologue. grid = 256, 1024 thr, 128000 B
// dynamic LDS. Prologue: private scan of cnt[b] -> pkl LDS overlay (buf0's
// first 32KB) -> pv + slot packs in regs -> barrier -> r16 window loop
// (buf0 fully overwritten by window-0 scatter).
__global__ __launch_bounds__(1024) void pool_kernel(const float* __restrict__ fe,
                                                    const int* __restrict__ gid,
                                                    const ushort* __restrict__ occ,
                                                    const int* __restrict__ cnt,
                                                    float* __restrict__ out) {
    extern __shared__ char smem[];
    uint* fes32 = (uint*)smem;          // 2 x 16000 u32 window buffers
    uint* pkl = (uint*)smem;            // prologue overlay: pkl[8000] (32KB)
    int* wpart = (int*)(smem + 64000);  // 16 wave partials (buf1 region)
    const int bid = blockIdx.x;
    const int b = bid >> 4, cg = bid & 15;
    const int tid = threadIdx.x;
    const int lane = tid & 63, wid = tid >> 6;
    const size_t bc0 = (size_t)(b * NC + cg * CPB);
    const bool t3 = (tid < 928);     // face tail: 4000 f32x4 per channel
    const bool t8 = (tid < 832);     // group tail: 8000 groups
    const int tl = t3 ? tid + 3072 : tid;   // uniform-load index (dummy=tid)

    // ---- prologue A: block-private exclusive scan of cnt[b] -> pkl ----
    // 1000 active threads x 8 counts; two-level scan (wave shfl + partials).
    int loc[8], nv[8];
    int ts = 0;
    if (tid < 1000) {
        const int4* c4 = (const int4*)(cnt + (size_t)b * NT + 8 * tid);
        int4 v0 = c4[0], v1 = c4[1];
        loc[0] = ts; nv[0] = v0.x; ts += v0.x;
        loc[1] = ts; nv[1] = v0.y; ts += v0.y;
        loc[2] = ts; nv[2] = v0.z; ts += v0.z;
        loc[3] = ts; nv[3] = v0.w; ts += v0.w;
        loc[4] = ts; nv[4] = v1.x; ts += v1.x;
        loc[5] = ts; nv[5] = v1.y; ts += v1.y;
        loc[6] = ts; nv[6] = v1.z; ts += v1.z;
        loc[7] = ts; nv[7] = v1.w; ts += v1.w;
    }
    int inc = ts;
    for (int d = 1; d < 64; d <<= 1) {
        int u = __shfl_up(inc, d);
        if (lane >= d) inc += u;
    }
    if (lane == 63) wpart[wid] = inc;
    __syncthreads();
    {
        int wbase = 0;
        for (int wv = 0; wv < wid; ++wv) wbase += wpart[wv];  // broadcast reads
        int base = wbase + inc - ts;   // exclusive prefix for this thread
        if (tid < 1000) {
#pragma unroll
            for (int j = 0; j < 8; ++j)
                pkl[8 * tid + j] = (uint)(base + loc[j]) | ((uint)nv[j] << 14);
        }
    }
    __syncthreads();   // pkl complete

    // ---- prologue B: pv + slot packs from pkl/gid/occ ----
    uint pv[8];
#pragma unroll
    for (int it = 0; it < 7; ++it) pv[it] = pkl[tid + it * 1024];
    pv[7] = 0;
    if (t8) pv[7] = pkl[7168 + tid];

    uint2 s0, s1, s2, s3;
    {
        const int4* g4 = (const int4*)(gid + (size_t)b * NF);
        const ushort4* o4 = (const ushort4*)(occ + (size_t)b * NF);
        int4 ga = g4[tid], gb4 = g4[tid + 1024];
        int4 gc = g4[tid + 2048], gd = g4[tl];
        ushort4 oa = o4[tid], ob = o4[tid + 1024];
        ushort4 oc = o4[tid + 2048], od = o4[tl];
#define SLOT(G, O) ((pkl[(uint)(G)] & 0x3FFFu) + (uint)(O))
        s0 = make_uint2(SLOT(ga.x, oa.x) | (SLOT(ga.y, oa.y) << 16),
                        SLOT(ga.z, oa.z) | (SLOT(ga.w, oa.w) << 16));
        s1 = make_uint2(SLOT(gb4.x, ob.x) | (SLOT(gb4.y, ob.y) << 16),
                        SLOT(gb4.z, ob.z) | (SLOT(gb4.w, ob.w) << 16));
        s2 = make_uint2(SLOT(gc.x, oc.x) | (SLOT(gc.y, oc.y) << 16),
                        SLOT(gc.z, oc.z) | (SLOT(gc.w, oc.w) << 16));
        s3 = make_uint2(SLOT(gd.x, od.x) | (SLOT(gd.y, od.y) << 16),
                        SLOT(gd.z, od.z) | (SLOT(gd.w, od.w) << 16));
#undef SLOT
    }
    __syncthreads();   // all pkl reads done; buf0 free for window-0 scatter

    // ---- r16 window loop (byte-identical) ----
    const f32x4* fe4base = (const f32x4*)(fe + bc0 * NF);
    f32x4 a0, a1, a2, a3, b0, b1, b2, b3;

    // prologue: issue pair-0 loads (channels 0,1) — plain loads (L3 hits)
    {
        const f32x4* fA = fe4base;
        const f32x4* fB = fe4base + (NF / 4);
        a0 = fA[tid]; a1 = fA[tid + 1024]; a2 = fA[tid + 2048]; a3 = fA[tl];
        b0 = fB[tid]; b1 = fB[tid + 1024]; b2 = fB[tid + 2048]; b3 = fB[tl];
    }

#define PAIR_WRITE(F, S, VA, VB) do {                                    \
        (F)[(S).x & 0xFFFFu] = cvtpk((VA)[0], (VB)[0]);                  \
        (F)[(S).x >> 16]     = cvtpk((VA)[1], (VB)[1]);                  \
        (F)[(S).y & 0xFFFFu] = cvtpk((VA)[2], (VB)[2]);                  \
        (F)[(S).y >> 16]     = cvtpk((VA)[3], (VB)[3]);                  \
    } while (0)

// Paired gather + direct coalesced NT dword stores (consecutive t across
// consecutive threads -> wave stores 256B contiguous, full lines).
#define GATHER_ST(F, P, T) do {                                          \
        uint p_ = (P);                                                   \
        uint off_ = p_ & 0x3FFFu, n_ = p_ >> 14;                         \
        float sa_ = 0.f, sb_ = 0.f;                                      \
        uint r_ = 0;                                                     \
        for (; r_ + 2 <= n_; r_ += 2) {                                  \
            uint2 w_;                                                    \
            __builtin_memcpy(&w_, &(F)[off_ + r_], 8);                   \
            sa_ += bf2f(w_.x & 0xFFFFu) + bf2f(w_.y & 0xFFFFu);          \
            sb_ += bf2f(w_.x >> 16) + bf2f(w_.y >> 16);                  \
        }                                                                \
        if (r_ < n_) {                                                   \
            uint w_ = (F)[off_ + r_];                                    \
            sa_ += bf2f(w_ & 0xFFFFu);                                   \
            sb_ += bf2f(w_ >> 16);                                       \
        }                                                                \
        float rn_ = n_ ? __builtin_amdgcn_rcpf((float)n_) : 0.f;         \
        __builtin_nontemporal_store(sa_ * rn_, &oA[T]);                  \
        __builtin_nontemporal_store(sb_ * rn_, &oB[T]);                  \
    } while (0)

#pragma unroll
    for (int k = 0; k < CPB / 2; ++k) {
        uint* F = fes32 + (k & 1) * 16000;

        // scatter pair k into buf(k&1); gather(k-1) read buf((k-1)&1) — no
        // conflict; barrier at window k-1 ordered gather(k-2) before this.
        PAIR_WRITE(F, s0, a0, b0);
        PAIR_WRITE(F, s1, a1, b1);
        PAIR_WRITE(F, s2, a2, b2);
        if (t3) PAIR_WRITE(F, s3, a3, b3);

        // prefetch next pair: uniform 8 loads, in flight across the window
        if (k + 1 < CPB / 2) {
            const f32x4* fA = fe4base + (size_t)(2 * k + 2) * (NF / 4);
            const f32x4* fB = fA + (NF / 4);
            a0 = fA[tid]; a1 = fA[tid + 1024]; a2 = fA[tid + 2048]; a3 = fA[tl];
            b0 = fB[tid]; b1 = fB[tid + 1024]; b2 = fB[tid + 2048]; b3 = fB[tl];
        }

        LGKM_BAR();   // scatter(k) visible to all; gather(k-1) complete too

        // gather + store means for both channels of pair k
        float* oA = out + (bc0 + (size_t)(2 * k)) * NT;
        float* oB = out + (bc0 + (size_t)(2 * k + 1)) * NT;
#pragma unroll
        for (int it = 0; it < 7; ++it) GATHER_ST(F, pv[it], tid + it * 1024);
        if (t8) GATHER_ST(F, pv[7], 7168 + tid);
    }
#undef GATHER_ST
#undef PAIR_WRITE
}

// Fallback (round-2 path) if workspace is too small.
__device__ __forceinline__ void lds_fadd(unsigned addr, float v) {
    asm volatile("ds_add_f32 %0, %1" :: "v"(addr), "v"(v));
}
__global__ __launch_bounds__(256) void pool_fused_kernel(const float* __restrict__ fe,
                                                         const int* __restrict__ gid,
                                                         float* __restrict__ out) {
    __shared__ float acc[NT];
    __shared__ int cnt[NT];
    const int bc = blockIdx.x, b = bc >> 8, tid = threadIdx.x;
    for (int t = tid; t < NT; t += 256) { acc[t] = 0.0f; cnt[t] = 0; }
    __syncthreads();
    const unsigned accb = (unsigned)(uintptr_t)acc;
    const float4* fe4 = (const float4*)(fe + (size_t)bc * NF);
    const int4* gid4 = (const int4*)(gid + (size_t)b * NF);
    for (int i = tid; i < NF / 4; i += 256) {
        float4 v = fe4[i];
        int4 g = gid4[i];
        lds_fadd(accb + 4u * (unsigned)g.x, v.x); atomicAdd(&cnt[g.x], 1);
        lds_fadd(accb + 4u * (unsigned)g.y, v.y); atomicAdd(&cnt[g.y], 1);
        lds_fadd(accb + 4u * (unsigned)g.z, v.z); atomicAdd(&cnt[g.z], 1);
        lds_fadd(accb + 4u * (unsigned)g.w, v.w); atomicAdd(&cnt[g.w], 1);
    }
    asm volatile("s_waitcnt lgkmcnt(0)" ::: "memory");
    __syncthreads();
    float* orow = out + (size_t)bc * NT;
    for (int t = tid; t < NT; t += 256) {
        int n = cnt[t];
        orow[t] = acc[t] / (float)(n > 0 ? n : 1);
    }
}

extern "C" void kernel_launch(void* const* d_in, const int* in_sizes, int n_in,
                              void* d_out, int out_size, void* d_ws, size_t ws_size,
                              hipStream_t stream) {
    const float* fe = (const float*)d_in[0];
    const int* gid = (const int*)d_in[1];
    float* out = (float*)d_out;

    // workspace layout (bytes)
    const size_t O_CNT = 0;          // int [NB*NT]   512000  (zeroed)
    const size_t O_OCC = 512000;     // u16 [NB*NF]   512000
    const size_t TOTAL = 1024000;

    if (ws_size >= TOTAL) {
        char* w = (char*)d_ws;
        int* cnt = (int*)(w + O_CNT);
        ushort* occ = (ushort*)(w + O_OCC);

        static bool lds_opted = false;
        if (!lds_opted) {
            (void)hipFuncSetAttribute((const void*)pool_kernel,
                                      hipFuncAttributeMaxDynamicSharedMemorySize,
                                      128000);
            lds_opted = true;
        }

        (void)hipMemsetAsync(cnt, 0, 512000, stream);
        hist_kernel<<<(NB * NF / 4 + 255) / 256, 256, 0, stream>>>(gid, cnt, occ);
        pool_kernel<<<NB * (NC / CPB), 1024, 128000, stream>>>(fe, gid, occ, cnt, out);
    } else {
        pool_fused_kernel<<<NB * NC, 256, 0, stream>>>(fe, gid, out);
    }
}